// Round 1
// baseline (241.930 us; speedup 1.0000x reference)
//
#include <hip/hip_runtime.h>
#include <math.h>

// CapsLayer dynamic routing, MI355X fp32.
// x: [64, 2048, 8]  W: [2048, 32, 8, 16]  out: [64, 32, 16]
// Strategy: never materialize u_hat (256 MB). Recompute per routing pass.

#define B_TOT 64
#define I_TOT 2048
#define D_IN  8
#define NC    32
#define EV    16
#define OD    (NC*EV)      // 512 outputs per (b,i)
#define BC    16           // batch rows per block
#define NBC   (B_TOT/BC)   // 4 b-chunks
#define ICH   16           // i's per block
#define NIC   (I_TOT/ICH)  // 128 i-chunks
#define WROW  136          // padded LDS row stride (floats) per capsule n

__device__ __forceinline__ void fma4(float4& acc, float a, const float4& w) {
    acc.x = fmaf(a, w.x, acc.x);
    acc.y = fmaf(a, w.y, acc.y);
    acc.z = fmaf(a, w.z, acc.z);
    acc.w = fmaf(a, w.w, acc.w);
}

// MODE 0: c uniform (iter 0)            -> P partials
// MODE 1: a = u.v0, softmax(a), store a -> P partials, aws
// MODE 2: a = u.v1 + a0(from aws), softmax -> P partials
template <int MODE>
__global__ __launch_bounds__(256, 2)
void route_pass(const float* __restrict__ x, const float* __restrict__ W,
                float* __restrict__ P, const float* __restrict__ vin,
                float* __restrict__ aws)
{
    __shared__ __align__(16) float Wl[NC * WROW];                       // 17.0 KB
    __shared__ __align__(16) float xl[BC * D_IN];                       // 512 B
    __shared__ __align__(16) float vl[(MODE >= 1) ? BC * OD : 4];       // 32 KB
    __shared__ __align__(16) float al[(MODE >= 1) ? BC * NC : 4];       // 2 KB
    __shared__ __align__(16) float a0l[(MODE == 2) ? BC * NC : 4];      // 2 KB
    __shared__ float rinv[BC];

    const int t  = threadIdx.x;
    const int bc = blockIdx.x & (NBC - 1);
    const int ic = blockIdx.x >> 2;
    const int b0 = bc * BC;
    const int i0 = ic * ICH;
    const int eq = t & 3;          // e quarter (4 e's)
    const int bh = (t >> 2) & 1;   // b half (8 b's)
    const int n  = t >> 3;         // capsule 0..31

    if (MODE >= 1) {
        // stage v table for this b-chunk: [BC][NC][EV] = 8192 floats
        #pragma unroll
        for (int k = 0; k < 8; ++k) {
            int j = (t + 256 * k) * 4;
            *(float4*)&vl[j] = *(const float4*)&vin[b0 * OD + j];
        }
    }

    float4 sacc[8];
    #pragma unroll
    for (int q = 0; q < 8; ++q) sacc[q] = make_float4(0.f, 0.f, 0.f, 0.f);

    for (int ii = 0; ii < ICH; ++ii) {
        const int i = i0 + ii;
        // ---- stage W[i] (4096 floats) into padded LDS rows ----
        #pragma unroll
        for (int k = 0; k < 4; ++k) {
            int fi = (t + 256 * k) * 4;                  // float index 0..4095
            float4 wv = *(const float4*)&W[(size_t)i * 4096 + fi];
            int nn = fi >> 7, r = fi & 127;
            *(float4*)&Wl[nn * WROW + r] = wv;
        }
        // ---- stage x[b0:b0+16, i, :] ----
        if (t < 32) {
            int bl = t >> 1, h = (t & 1) * 4;
            *(float4*)&xl[bl * D_IN + h] =
                *(const float4*)&x[((size_t)(b0 + bl) * I_TOT + i) * D_IN + h];
        }
        // ---- stage a0 (MODE 2) ----
        if (MODE == 2) {
            *(float2*)&a0l[t * 2] =
                *(const float2*)&aws[((size_t)i * NBC + bc) * OD + t * 2];
        }
        __syncthreads();

        // ---- load this thread's W fragment: [8 d][4 e] ----
        float4 wr[8];
        #pragma unroll
        for (int d = 0; d < 8; ++d)
            wr[d] = *(float4*)&Wl[n * WROW + d * 16 + eq * 4];

        // ---- compute u[bl][4e] for 8 batch rows ----
        float4 u[8];
        #pragma unroll
        for (int q = 0; q < 8; ++q) {
            const int bl = bh * 8 + q;
            float4 xa = *(float4*)&xl[bl * D_IN];
            float4 xb = *(float4*)&xl[bl * D_IN + 4];
            float4 uu = make_float4(0.f, 0.f, 0.f, 0.f);
            fma4(uu, xa.x, wr[0]); fma4(uu, xa.y, wr[1]);
            fma4(uu, xa.z, wr[2]); fma4(uu, xa.w, wr[3]);
            fma4(uu, xb.x, wr[4]); fma4(uu, xb.y, wr[5]);
            fma4(uu, xb.z, wr[6]); fma4(uu, xb.w, wr[7]);
            u[q] = uu;
        }

        if (MODE == 0) {
            #pragma unroll
            for (int q = 0; q < 8; ++q) {
                sacc[q].x += u[q].x; sacc[q].y += u[q].y;
                sacc[q].z += u[q].z; sacc[q].w += u[q].w;
            }
            __syncthreads();   // protect Wl/xl before next stage
        } else {
            // ---- a[bl][n] = dot(u, v) reduced over e (4 in-thread + 2 shfl) ----
            #pragma unroll
            for (int q = 0; q < 8; ++q) {
                const int bl = bh * 8 + q;
                float4 vv = *(float4*)&vl[bl * OD + n * EV + eq * 4];
                float ap = u[q].x * vv.x + u[q].y * vv.y + u[q].z * vv.z + u[q].w * vv.w;
                ap += __shfl_xor(ap, 1, 64);
                ap += __shfl_xor(ap, 2, 64);
                if (eq == 0) {
                    float av = ap;
                    if (MODE == 2) av += a0l[bl * NC + n];
                    al[bl * NC + n] = av;
                }
            }
            __syncthreads();
            // ---- softmax over n per (bl): exp + rowsum via 16-lane shuffle ----
            {
                const int bl = t >> 4, j = t & 15;
                float r1 = al[bl * NC + j];
                float r2 = al[bl * NC + j + 16];
                if (MODE == 1) {
                    float* dst = &aws[((size_t)i * NBC + bc) * OD + bl * NC + j];
                    dst[0]  = r1;
                    dst[16] = r2;
                }
                float e1 = expf(r1), e2 = expf(r2);
                al[bl * NC + j]      = e1;
                al[bl * NC + j + 16] = e2;
                float s = e1 + e2;
                s += __shfl_xor(s, 1, 64);
                s += __shfl_xor(s, 2, 64);
                s += __shfl_xor(s, 4, 64);
                s += __shfl_xor(s, 8, 64);
                if (j == 0) rinv[bl] = 1.0f / s;
            }
            __syncthreads();
            // ---- accumulate c * u ----
            #pragma unroll
            for (int q = 0; q < 8; ++q) {
                const int bl = bh * 8 + q;
                float c = al[bl * NC + n] * rinv[bl];
                fma4(sacc[q], c, u[q]);
            }
            __syncthreads();   // protect al/rinv/Wl/xl before next i
        }
    }

    // ---- write partials: P[ic][b][o] ----
    #pragma unroll
    for (int q = 0; q < 8; ++q) {
        const int bl = bh * 8 + q;
        *(float4*)&P[((size_t)ic * B_TOT + b0 + bl) * OD + n * EV + eq * 4] = sacc[q];
    }
}

// Reduce partials over i-chunks, then squash per (b, n). One block per b.
__global__ __launch_bounds__(256, 4)
void reduce_squash(const float* __restrict__ P, float* __restrict__ dst, float pre)
{
    const int b = blockIdx.x;
    const int t = threadIdx.x;
    float s1 = 0.f, s2 = 0.f;
    for (int ic = 0; ic < NIC; ++ic) {
        const float* p = &P[((size_t)ic * B_TOT + b) * OD];
        s1 += p[t];
        s2 += p[t + 256];
    }
    s1 *= pre; s2 *= pre;
    // squared norm over e (16 consecutive lanes)
    float q1 = s1 * s1, q2 = s2 * s2;
    q1 += __shfl_xor(q1, 1, 64);  q2 += __shfl_xor(q2, 1, 64);
    q1 += __shfl_xor(q1, 2, 64);  q2 += __shfl_xor(q2, 2, 64);
    q1 += __shfl_xor(q1, 4, 64);  q2 += __shfl_xor(q2, 4, 64);
    q1 += __shfl_xor(q1, 8, 64);  q2 += __shfl_xor(q2, 8, 64);
    float sc1 = q1 / ((1.0f + q1) * sqrtf(q1));
    float sc2 = q2 / ((1.0f + q2) * sqrtf(q2));
    dst[b * OD + t]       = s1 * sc1;
    dst[b * OD + t + 256] = s2 * sc2;
}

extern "C" void kernel_launch(void* const* d_in, const int* in_sizes, int n_in,
                              void* d_out, int out_size, void* d_ws, size_t ws_size,
                              hipStream_t stream) {
    const float* x = (const float*)d_in[0];
    const float* W = (const float*)d_in[1];
    float* out = (float*)d_out;

    char* ws = (char*)d_ws;
    float* P   = (float*)ws;                               // NIC*64*512*4   = 16 MB
    float* aws = (float*)(ws + (size_t)16 * 1024 * 1024);  // 2048*4*512*4   = 16 MB
    float* v0  = (float*)(ws + (size_t)32 * 1024 * 1024);  // 64*512*4       = 128 KB
    float* v1  = v0 + B_TOT * OD;

    dim3 grid(NBC * NIC), blk(256);

    // iter 0: uniform c = 1/32
    route_pass<0><<<grid, blk, 0, stream>>>(x, W, P, nullptr, nullptr);
    reduce_squash<<<B_TOT, 256, 0, stream>>>(P, v0, 1.0f / 32.0f);
    // iter 1: c = softmax(dot(u, v0)); store logits a0
    route_pass<1><<<grid, blk, 0, stream>>>(x, W, P, v0, aws);
    reduce_squash<<<B_TOT, 256, 0, stream>>>(P, v1, 1.0f);
    // iter 2: c = softmax(a0 + dot(u, v1)); final
    route_pass<2><<<grid, blk, 0, stream>>>(x, W, P, v1, aws);
    reduce_squash<<<B_TOT, 256, 0, stream>>>(P, out, 1.0f);
}

// Round 2
// 198.670 us; speedup vs baseline: 1.2177x; 1.2177x over previous
//
#include <hip/hip_runtime.h>
#include <math.h>

// CapsLayer dynamic routing, MI355X fp32.
// x: [64, 2048, 8]  W: [2048, 32, 8, 16]  out: [64, 32, 16]
// Never materialize u_hat (256 MB); recompute per routing pass.
// R2: latency-bound fix — BC=8 (grid 1024, 4 blocks/CU), W read straight from
// global (L2-hot, no LDS staging, no staging barriers), in-wave softmax with
// 256B double-buffered partial exchange (1 barrier/i in MODE1/2, 0 in MODE0),
// XCD swizzle so b-chunk siblings share one XCD's L2 for W.

#define B_TOT 64
#define I_TOT 2048
#define D_IN  8
#define NC    32
#define EV    16
#define OD    (NC*EV)      // 512 outputs per (b,i)
#define BC    8            // batch rows per block
#define NBC   (B_TOT/BC)   // 8 b-chunks
#define ICH   16           // i's per block
#define NIC   (I_TOT/ICH)  // 128 i-chunks

__device__ __forceinline__ void fma4(float4& acc, float a, const float4& w) {
    acc.x = fmaf(a, w.x, acc.x);
    acc.y = fmaf(a, w.y, acc.y);
    acc.z = fmaf(a, w.z, acc.z);
    acc.w = fmaf(a, w.w, acc.w);
}

// MODE 0: c uniform (iter 0)                    -> P partials
// MODE 1: a = u.v0, softmax(a), store a to aws  -> P partials
// MODE 2: a = u.v1 + a0(from aws), softmax      -> P partials
template <int MODE>
__global__ __launch_bounds__(256, 4)
void route_pass(const float* __restrict__ x, const float* __restrict__ W,
                float* __restrict__ P, const float* __restrict__ vin,
                float* __restrict__ aws)
{
    __shared__ __align__(16) float xl[BC * ICH * D_IN];   // 4 KB
    __shared__ float wsum[2][4][BC];                      // 256 B (double-buffered)

    const int t  = threadIdx.x;
    // XCD swizzle: blk%8 picks the XCD; keep it == f(ic) so the 8 bc-siblings
    // of an ic (which share W[i0..i0+15]) land on the same XCD's L2.
    const int ic = blockIdx.x & (NIC - 1);   // 0..127
    const int bc = blockIdx.x >> 7;          // 0..7
    const int b0 = bc * BC;
    const int i0 = ic * ICH;
    const int eq = t & 3;          // e quarter (4 e's)
    const int bh = (t >> 2) & 1;   // b half (4 b's each)
    const int n  = t >> 3;         // capsule 0..31 (lane bits 3..5 within wave)
    const int w  = t >> 6;         // wave 0..3

    // ---- stage x[b0..b0+7][i0..i0+15][0..7] once (4 KB) ----
    {
        const int row = t >> 5, f = (t & 31) * 4;
        *(float4*)&xl[row * (ICH * D_IN) + f] =
            *(const float4*)&x[((size_t)(b0 + row) * I_TOT + i0) * D_IN + f];
    }

    // ---- v fragments in registers (loaded once; L2-hot, tiny) ----
    float4 vr[4];
    if (MODE >= 1) {
        #pragma unroll
        for (int q = 0; q < 4; ++q)
            vr[q] = *(const float4*)&vin[(size_t)(b0 + bh * 4 + q) * OD + n * EV + eq * 4];
    }
    __syncthreads();

    float4 sacc[4];
    #pragma unroll
    for (int q = 0; q < 4; ++q) sacc[q] = make_float4(0.f, 0.f, 0.f, 0.f);

    const float* Wt = &W[(size_t)i0 * 4096 + n * 128 + eq * 4];

    for (int ii = 0; ii < ICH; ++ii) {
        // ---- this thread's W fragment straight from global (64B-coalesced) ----
        float4 wr[8];
        #pragma unroll
        for (int d = 0; d < 8; ++d)
            wr[d] = *(const float4*)&Wt[ii * 4096 + d * 16];

        // ---- u[bl][eq*4..+3] for 4 batch rows ----
        float4 u[4];
        #pragma unroll
        for (int q = 0; q < 4; ++q) {
            const int bl = bh * 4 + q;
            float4 xa = *(float4*)&xl[bl * (ICH * D_IN) + ii * 8];
            float4 xb = *(float4*)&xl[bl * (ICH * D_IN) + ii * 8 + 4];
            float4 uu = make_float4(0.f, 0.f, 0.f, 0.f);
            fma4(uu, xa.x, wr[0]); fma4(uu, xa.y, wr[1]);
            fma4(uu, xa.z, wr[2]); fma4(uu, xa.w, wr[3]);
            fma4(uu, xb.x, wr[4]); fma4(uu, xb.y, wr[5]);
            fma4(uu, xb.z, wr[6]); fma4(uu, xb.w, wr[7]);
            u[q] = uu;
        }

        if (MODE == 0) {
            #pragma unroll
            for (int q = 0; q < 4; ++q) {
                sacc[q].x += u[q].x; sacc[q].y += u[q].y;
                sacc[q].z += u[q].z; sacc[q].w += u[q].w;
            }
            // no barrier: xl is read-only, no LDS communication
        } else {
            // ---- a[bl] = dot(u, v) over e: 4 in-thread + shfl over eq bits ----
            float a[4];
            #pragma unroll
            for (int q = 0; q < 4; ++q) {
                float ap = u[q].x * vr[q].x + u[q].y * vr[q].y
                         + u[q].z * vr[q].z + u[q].w * vr[q].w;
                ap += __shfl_xor(ap, 1, 64);
                ap += __shfl_xor(ap, 2, 64);
                a[q] = ap;
            }
            const size_t aoff = (((size_t)(i0 + ii) * NBC + bc) * NC + n) * 8 + bh * 4;
            if (MODE == 2) {
                float4 a0 = *(const float4*)&aws[aoff];
                a[0] += a0.x; a[1] += a0.y; a[2] += a0.z; a[3] += a0.w;
            }
            if (MODE == 1 && eq == 0) {
                float4 st = make_float4(a[0], a[1], a[2], a[3]);
                *(float4*)&aws[aoff] = st;
            }
            // ---- softmax over n: exp, in-wave partial over this wave's 8 n's ----
            float e[4], p[4];
            #pragma unroll
            for (int q = 0; q < 4; ++q) {
                e[q] = __expf(a[q]);
                float pp = e[q];
                pp += __shfl_xor(pp, 8, 64);
                pp += __shfl_xor(pp, 16, 64);
                pp += __shfl_xor(pp, 32, 64);
                p[q] = pp;       // sum over n in this wave, for bl = bh*4+q
            }
            if (eq == 0) {
                #pragma unroll
                for (int q = 0; q < 4; ++q)
                    wsum[ii & 1][w][bh * 4 + q] = p[q];
            }
            __syncthreads();     // the ONLY barrier per i (wsum double-buffered)
            #pragma unroll
            for (int q = 0; q < 4; ++q) {
                const int bl = bh * 4 + q;
                float s = wsum[ii & 1][0][bl] + wsum[ii & 1][1][bl]
                        + wsum[ii & 1][2][bl] + wsum[ii & 1][3][bl];
                float c = e[q] / s;
                fma4(sacc[q], c, u[q]);
            }
        }
    }

    // ---- write partials: P[ic][b][o] (64B-coalesced) ----
    #pragma unroll
    for (int q = 0; q < 4; ++q)
        *(float4*)&P[((size_t)ic * B_TOT + b0 + bh * 4 + q) * OD + n * EV + eq * 4] = sacc[q];
}

// Reduce partials over i-chunks, then squash per (b, n). One block per b.
__global__ __launch_bounds__(256, 4)
void reduce_squash(const float* __restrict__ P, float* __restrict__ dst, float pre)
{
    const int b = blockIdx.x;
    const int t = threadIdx.x;
    float s1 = 0.f, s2 = 0.f;
    for (int ic = 0; ic < NIC; ++ic) {
        const float* p = &P[((size_t)ic * B_TOT + b) * OD];
        s1 += p[t];
        s2 += p[t + 256];
    }
    s1 *= pre; s2 *= pre;
    // squared norm over e (16 consecutive lanes)
    float q1 = s1 * s1, q2 = s2 * s2;
    q1 += __shfl_xor(q1, 1, 64);  q2 += __shfl_xor(q2, 1, 64);
    q1 += __shfl_xor(q1, 2, 64);  q2 += __shfl_xor(q2, 2, 64);
    q1 += __shfl_xor(q1, 4, 64);  q2 += __shfl_xor(q2, 4, 64);
    q1 += __shfl_xor(q1, 8, 64);  q2 += __shfl_xor(q2, 8, 64);
    float sc1 = q1 / ((1.0f + q1) * sqrtf(q1));
    float sc2 = q2 / ((1.0f + q2) * sqrtf(q2));
    dst[b * OD + t]       = s1 * sc1;
    dst[b * OD + t + 256] = s2 * sc2;
}

extern "C" void kernel_launch(void* const* d_in, const int* in_sizes, int n_in,
                              void* d_out, int out_size, void* d_ws, size_t ws_size,
                              hipStream_t stream) {
    const float* x = (const float*)d_in[0];
    const float* W = (const float*)d_in[1];
    float* out = (float*)d_out;

    char* ws = (char*)d_ws;
    float* P   = (float*)ws;                               // NIC*64*512*4   = 16 MB
    float* aws = (float*)(ws + (size_t)16 * 1024 * 1024);  // 2048*8*32*8*4  = 16 MB
    float* v0  = (float*)(ws + (size_t)32 * 1024 * 1024);  // 64*512*4       = 128 KB
    float* v1  = v0 + B_TOT * OD;

    dim3 grid(NBC * NIC), blk(256);   // 1024 blocks = 4 per CU

    // iter 0: uniform c = 1/32
    route_pass<0><<<grid, blk, 0, stream>>>(x, W, P, nullptr, nullptr);
    reduce_squash<<<B_TOT, 256, 0, stream>>>(P, v0, 1.0f / 32.0f);
    // iter 1: c = softmax(dot(u, v0)); store logits a0
    route_pass<1><<<grid, blk, 0, stream>>>(x, W, P, v0, aws);
    reduce_squash<<<B_TOT, 256, 0, stream>>>(P, v1, 1.0f);
    // iter 2: c = softmax(a0 + dot(u, v1)); final
    route_pass<2><<<grid, blk, 0, stream>>>(x, W, P, v1, aws);
    reduce_squash<<<B_TOT, 256, 0, stream>>>(P, out, 1.0f);
}